// Round 1
// baseline (506.865 us; speedup 1.0000x reference)
//
#include <hip/hip_runtime.h>
#include <hip/hip_bf16.h>
#include <math.h>

// Problem constants (reference: B,T,E,WIN,OC,VOCAB = 256,2048,128,5,128,50000)
#define B_   256
#define T_   2048
#define E_   128
#define WIN_ 5
#define PAD_ 2
#define OC_  128
#define TT   64                 // tokens per block tile
#define ROWS (TT + WIN_ - 1)    // 68 rows incl. halo
#define STR  132                // padded LDS row stride (floats): breaks bank conflicts

__global__ void init_ws_kernel(float* ws) {
    int i = blockIdx.x * blockDim.x + threadIdx.x;
    if (i < B_ * OC_) ws[i] = -INFINITY;
}

__device__ inline void atomicMaxFloat(float* addr, float v) {
    // IEEE-754 order trick: positive floats compare as ints, negative as reversed unsigned
    if (v >= 0.0f) atomicMax((int*)addr, __float_as_int(v));
    else           atomicMin((unsigned int*)addr, __float_as_uint(v));
}

__launch_bounds__(256, 2)
__global__ void local_attn_main(const int* __restrict__ x,
                                const float* __restrict__ emb,
                                const float* __restrict__ att_w,
                                const float* __restrict__ att_b,
                                const float* __restrict__ cnn_w,
                                float* __restrict__ ws) {
    __shared__ float sh_emb[ROWS * STR];     // 35.9 KB
    __shared__ float sh_w[32 * STR];         // 16.9 KB  (one 32-o chunk of cnn_w)
    __shared__ float sh_att[WIN_ * E_];      // 2.5 KB
    __shared__ float sh_r[ROWS * WIN_];      // per-row per-tap dots
    __shared__ float sh_score[TT];
    __shared__ float sh_red[32 * 17];        // padded reduction scratch
    __shared__ int   sh_idx[ROWS];

    const int tid  = threadIdx.x;
    const int tile = blockIdx.x;             // 0..T/TT-1
    const int b    = blockIdx.y;             // 0..B-1
    const int t0   = tile * TT;

    // ---- Phase 0: token indices + att_w staging ----
    if (tid < ROWS) {
        int gt = t0 + tid - PAD_;
        sh_idx[tid] = (gt >= 0 && gt < T_) ? x[b * T_ + gt] : -1;  // -1 => zero pad row
    }
    if (tid < WIN_ * E_ / 4) {
        *(float4*)(sh_att + tid * 4) = *(const float4*)(att_w + tid * 4);
    }
    __syncthreads();

    // ---- Phase 1: gather embedding rows into LDS (coalesced float4, 8 rows/pass) ----
    for (int r0 = 0; r0 < ROWS; r0 += 8) {
        int row  = r0 + (tid >> 5);
        int slot = tid & 31;                 // 32 float4 slots cover a 128-float row
        if (row < ROWS) {
            int idx = sh_idx[row];
            float4 v = make_float4(0.f, 0.f, 0.f, 0.f);
            if (idx >= 0) v = *(const float4*)(emb + (size_t)idx * E_ + slot * 4);
            *(float4*)(sh_emb + row * STR + slot * 4) = v;
        }
    }
    __syncthreads();

    // ---- Phase 2: r[row][k] = <emb_row, att_w[k]>, then sliding window -> sigmoid ----
    for (int d = tid; d < ROWS * WIN_; d += 256) {
        int row = d % ROWS;                  // adjacent lanes -> adjacent rows (padded: conflict-free)
        int k   = d / ROWS;
        const float4* er = (const float4*)(sh_emb + row * STR);
        const float4* wr = (const float4*)(sh_att + k * E_);
        float s = 0.f;
        #pragma unroll
        for (int e = 0; e < E_ / 4; e++) {
            float4 a = er[e], w = wr[e];
            s += a.x * w.x + a.y * w.y + a.z * w.z + a.w * w.w;
        }
        sh_r[row * WIN_ + k] = s;
    }
    __syncthreads();
    if (tid < TT) {
        float s = 0.f;
        #pragma unroll
        for (int k = 0; k < WIN_; k++) s += sh_r[(tid + k) * WIN_ + k];
        s += att_b[0];
        sh_score[tid] = 1.0f / (1.0f + __expf(-s));
    }
    // (sh_score read is protected by the sync after the first sh_w load below)

    // ---- Phase 3: C[t][o] = <emb[t], cnn_w[o]>, scale by score, running max ----
    const int og = tid & 15;                 // 16 o-groups x 2 o
    const int tg = tid >> 4;                 // 16 t-groups x 4 t

    for (int oc = 0; oc < 4; oc++) {
        __syncthreads();                     // sh_w / sh_red reuse barrier
        #pragma unroll
        for (int p = 0; p < 4; p++) {        // stage 32 rows of cnn_w
            int rl   = p * 8 + (tid >> 5);
            int slot = tid & 31;
            *(float4*)(sh_w + rl * STR + slot * 4) =
                *(const float4*)(cnn_w + (size_t)(oc * 32 + rl) * E_ + slot * 4);
        }
        __syncthreads();

        float acc[4][2] = {};
        const float4* w0 = (const float4*)(sh_w + (og * 2 + 0) * STR);
        const float4* w1 = (const float4*)(sh_w + (og * 2 + 1) * STR);
        for (int e = 0; e < E_ / 4; e++) {
            float4 wv0 = w0[e], wv1 = w1[e];
            #pragma unroll
            for (int i = 0; i < 4; i++) {
                float4 a = *(const float4*)(sh_emb + (tg * 4 + i + PAD_) * STR + e * 4);
                acc[i][0] += a.x * wv0.x + a.y * wv0.y + a.z * wv0.z + a.w * wv0.w;
                acc[i][1] += a.x * wv1.x + a.y * wv1.y + a.z * wv1.z + a.w * wv1.w;
            }
        }

        float m0 = -INFINITY, m1 = -INFINITY;
        #pragma unroll
        for (int i = 0; i < 4; i++) {
            float sc = sh_score[tg * 4 + i];
            m0 = fmaxf(m0, sc * acc[i][0]);
            m1 = fmaxf(m1, sc * acc[i][1]);
        }
        sh_red[(og * 2 + 0) * 17 + tg] = m0;
        sh_red[(og * 2 + 1) * 17 + tg] = m1;
        __syncthreads();
        if (tid < 32) {
            float m = sh_red[tid * 17];
            #pragma unroll
            for (int q = 1; q < 16; q++) m = fmaxf(m, sh_red[tid * 17 + q]);
            atomicMaxFloat(&ws[b * OC_ + oc * 32 + tid], m);
        }
    }
}

__global__ void finalize_kernel(const float* __restrict__ ws,
                                const float* __restrict__ cnn_b,
                                float* __restrict__ out) {
    int i = blockIdx.x * blockDim.x + threadIdx.x;
    if (i < B_ * OC_) out[i] = tanhf(ws[i] + cnn_b[i & (OC_ - 1)]);
}

extern "C" void kernel_launch(void* const* d_in, const int* in_sizes, int n_in,
                              void* d_out, int out_size, void* d_ws, size_t ws_size,
                              hipStream_t stream) {
    const int*   x     = (const int*)d_in[0];
    const float* emb   = (const float*)d_in[1];
    const float* att_w = (const float*)d_in[2];
    const float* att_b = (const float*)d_in[3];
    const float* cnn_w = (const float*)d_in[4];
    const float* cnn_b = (const float*)d_in[5];
    float* out = (float*)d_out;
    float* ws  = (float*)d_ws;               // [B, OC] running max, re-init every launch

    init_ws_kernel<<<(B_ * OC_ + 255) / 256, 256, 0, stream>>>(ws);
    dim3 grid(T_ / TT, B_);
    local_attn_main<<<grid, 256, 0, stream>>>(x, emb, att_w, att_b, cnn_w, ws);
    finalize_kernel<<<(B_ * OC_ + 255) / 256, 256, 0, stream>>>(ws, cnn_b, out);
}

// Round 2
// 185.402 us; speedup vs baseline: 2.7339x; 2.7339x over previous
//
#include <hip/hip_runtime.h>
#include <hip/hip_bf16.h>
#include <math.h>

// B,T,E,WIN,OC,VOCAB = 256,2048,128,5,128,50000
#define B_   256
#define T_   2048
#define E_   128
#define WIN_ 5
#define PAD_ 2
#define OC_  128
#define TT   64                  // tokens per block
#define REAL_ROWS (TT + WIN_ - 1)  // 68 rows incl. halo
#define ROWS 80                  // padded to 5 m-tiles of 16
#define ASTR 136                 // LDS row stride in bf16 (272 B: 2-way bank alias = free)

typedef __attribute__((ext_vector_type(8))) short short8;
typedef __attribute__((ext_vector_type(4))) float floatx4;

static __device__ __forceinline__ short f2bf(float f) {
    union { __hip_bfloat16 h; short s; } u;
    u.h = __float2bfloat16(f);
    return u.s;
}

__device__ __forceinline__ void atomicMaxFloat(float* addr, float v) {
    if (v >= 0.0f) atomicMax((int*)addr, __float_as_int(v));
    else           atomicMin((unsigned int*)addr, __float_as_uint(v));
}

// k0: convert cnn_w / att_w to bf16 in ws; init out to -inf (max accumulator)
__global__ void prep_kernel(const float* __restrict__ cnn_w,
                            const float* __restrict__ att_w,
                            short* __restrict__ ws_w, short* __restrict__ ws_att,
                            float* __restrict__ out) {
    int i = blockIdx.x * 256 + threadIdx.x;          // 0..32767
    if (i < OC_ * E_)  ws_w[i]   = f2bf(cnn_w[i]);
    if (i < WIN_ * E_) ws_att[i] = f2bf(att_w[i]);
    if (i < B_ * OC_)  out[i]    = -INFINITY;
}

__launch_bounds__(256, 2)
__global__ void local_attn_main(const int* __restrict__ x,
                                const float* __restrict__ emb,
                                const float* __restrict__ att_b_p,
                                const short* __restrict__ wsw,
                                const short* __restrict__ wsatt,
                                float* __restrict__ out) {
    __shared__ short sh_a[ROWS * ASTR];    // 21760 B  (bf16 embed rows, token t at row t+PAD_)
    __shared__ short sh_w[OC_ * ASTR];     // 34816 B  (bf16 cnn_w rows)
    __shared__ short sh_att[16 * ASTR];    // 4352 B   (taps 0-4 real, 5-15 zero)
    __shared__ float sh_r[ROWS * 8];       // 2560 B   (per-row per-tap dots)
    __shared__ float sh_score[TT];
    __shared__ int   sh_idx[ROWS];

    const int tid  = threadIdx.x;
    const int lane = tid & 63;
    const int w    = tid >> 6;             // wave 0..3
    const int b    = blockIdx.y;
    const int t0   = blockIdx.x * TT;
    const int l15  = lane & 15;
    const int quad = lane >> 4;

    // ---- token indices ----
    if (tid < ROWS) {
        int gt = t0 + tid - PAD_;
        sh_idx[tid] = (tid < REAL_ROWS && gt >= 0 && gt < T_) ? x[b * T_ + gt] : -1;
    }
    __syncthreads();

    // ---- gather embed rows -> bf16 LDS (8 rows/pass, float4 loads) ----
    for (int r0 = 0; r0 < ROWS; r0 += 8) {
        int row  = r0 + (tid >> 5);
        int slot = tid & 31;               // 32 x float4 per 128-float row
        int idx  = sh_idx[row];
        float4 v = make_float4(0.f, 0.f, 0.f, 0.f);
        if (idx >= 0) v = *(const float4*)(emb + (size_t)idx * E_ + slot * 4);
        short4 o;
        o.x = f2bf(v.x); o.y = f2bf(v.y); o.z = f2bf(v.z); o.w = f2bf(v.w);
        *(short4*)(&sh_a[row * ASTR + slot * 4]) = o;
    }

    // ---- stage cnn_w (bf16, pre-converted) -> LDS ----
    for (int i = tid; i < OC_ * 16; i += 256) {     // 2048 x 16B chunks
        int o = i >> 4, c = i & 15;
        short8 v = *(const short8*)(wsw + o * E_ + c * 8);
        *(short8*)(&sh_w[o * ASTR + c * 8]) = v;
    }

    // ---- stage att_w (bf16) -> LDS, zero-padded to 16 taps ----
    {
        int o = tid >> 4, c = tid & 15;             // 16 rows x 16 chunks
        short8 v = (short8){0,0,0,0,0,0,0,0};
        if (o < WIN_) v = *(const short8*)(wsatt + o * E_ + c * 8);
        *(short8*)(&sh_att[o * ASTR + c * 8]) = v;
    }
    __syncthreads();

    // ---- scores via MFMA: r[row][tap] = <emb_row, att_w[tap]> ----
    short8 bs[4];
    #pragma unroll
    for (int ks = 0; ks < 4; ks++)
        bs[ks] = *(const short8*)(&sh_att[l15 * ASTR + ks * 32 + quad * 8]);

    for (int mt = w; mt < 5; mt += 4) {             // 5 m-tiles over 80 rows
        floatx4 acc = (floatx4){0.f, 0.f, 0.f, 0.f};
        #pragma unroll
        for (int ks = 0; ks < 4; ks++) {
            short8 a = *(const short8*)(&sh_a[(mt * 16 + l15) * ASTR + ks * 32 + quad * 8]);
            acc = __builtin_amdgcn_mfma_f32_16x16x32_bf16(a, bs[ks], acc, 0, 0, 0);
        }
        if (l15 < 8) {                              // taps 0..7 (only 0..4 used)
            #pragma unroll
            for (int r = 0; r < 4; r++)
                sh_r[(mt * 16 + quad * 4 + r) * 8 + l15] = acc[r];
        }
    }
    __syncthreads();

    if (tid < TT) {
        float s = att_b_p[0];
        #pragma unroll
        for (int k = 0; k < WIN_; k++) s += sh_r[(tid + k) * 8 + k];
        sh_score[tid] = 1.0f / (1.0f + __expf(-s));
    }
    __syncthreads();

    // ---- main GEMM: wave = 2 m-tiles x 4 n-tiles of 16x16x32 ----
    const int w0 = w & 1;                  // m half: rows [w0*32, w0*32+32)
    const int w1 = w >> 1;                 // n half: cols [w1*64, w1*64+64)

    floatx4 acc[2][4];
    #pragma unroll
    for (int i = 0; i < 2; i++)
        #pragma unroll
        for (int j = 0; j < 4; j++) acc[i][j] = (floatx4){0.f, 0.f, 0.f, 0.f};

    #pragma unroll
    for (int ks = 0; ks < 4; ks++) {
        int ko = ks * 32 + quad * 8;
        short8 a0 = *(const short8*)(&sh_a[(PAD_ + w0 * 32 +  0 + l15) * ASTR + ko]);
        short8 a1 = *(const short8*)(&sh_a[(PAD_ + w0 * 32 + 16 + l15) * ASTR + ko]);
        #pragma unroll
        for (int j = 0; j < 4; j++) {
            short8 bj = *(const short8*)(&sh_w[(w1 * 64 + j * 16 + l15) * ASTR + ko]);
            acc[0][j] = __builtin_amdgcn_mfma_f32_16x16x32_bf16(a0, bj, acc[0][j], 0, 0, 0);
            acc[1][j] = __builtin_amdgcn_mfma_f32_16x16x32_bf16(a1, bj, acc[1][j], 0, 0, 0);
        }
    }

    // ---- scale by sigmoid score, max over rows, atomicMax into out ----
    float sc[2][4];
    #pragma unroll
    for (int i = 0; i < 2; i++)
        #pragma unroll
        for (int r = 0; r < 4; r++)
            sc[i][r] = sh_score[w0 * 32 + i * 16 + quad * 4 + r];

    #pragma unroll
    for (int j = 0; j < 4; j++) {
        float mm = -INFINITY;
        #pragma unroll
        for (int i = 0; i < 2; i++)
            #pragma unroll
            for (int r = 0; r < 4; r++)
                mm = fmaxf(mm, sc[i][r] * acc[i][j][r]);
        mm = fmaxf(mm, __shfl_xor(mm, 16));
        mm = fmaxf(mm, __shfl_xor(mm, 32));
        if (lane < 16)
            atomicMaxFloat(&out[b * OC_ + w1 * 64 + j * 16 + lane], mm);
    }
}

// k2: out = tanh(max + bias), in place
__global__ void finalize_kernel(const float* __restrict__ cnn_b, float* __restrict__ out) {
    int i = blockIdx.x * 256 + threadIdx.x;
    if (i < B_ * OC_) out[i] = tanhf(out[i] + cnn_b[i & (OC_ - 1)]);
}

extern "C" void kernel_launch(void* const* d_in, const int* in_sizes, int n_in,
                              void* d_out, int out_size, void* d_ws, size_t ws_size,
                              hipStream_t stream) {
    const int*   x     = (const int*)d_in[0];
    const float* emb   = (const float*)d_in[1];
    const float* att_w = (const float*)d_in[2];
    const float* att_b = (const float*)d_in[3];
    const float* cnn_w = (const float*)d_in[4];
    const float* cnn_b = (const float*)d_in[5];
    float* out = (float*)d_out;

    short* ws_w   = (short*)d_ws;                 // [OC_*E_] bf16
    short* ws_att = ws_w + OC_ * E_;              // [WIN_*E_] bf16

    prep_kernel<<<128, 256, 0, stream>>>(cnn_w, att_w, ws_w, ws_att, out);
    dim3 grid(T_ / TT, B_);
    local_attn_main<<<grid, 256, 0, stream>>>(x, emb, att_b, ws_w, ws_att, out);
    finalize_kernel<<<(B_ * OC_ + 255) / 256, 256, 0, stream>>>(cnn_b, out);
}

// Round 3
// 143.271 us; speedup vs baseline: 3.5378x; 1.2941x over previous
//
#include <hip/hip_runtime.h>
#include <hip/hip_bf16.h>
#include <math.h>

// B,T,E,WIN,OC,VOCAB = 256,2048,128,5,128,50000
#define B_   256
#define T_   2048
#define E_   128
#define WIN_ 5
#define PAD_ 2
#define OC_  128
#define VOCAB1 50001
#define NT   4                    // 64-token tiles per block
#define TT   64
#define BTOK (NT * TT)            // 256 tokens per block
#define REAL_ROWS (TT + WIN_ - 1) // 68 rows incl. halo
#define ROWS 80                   // padded to 5 m-tiles of 16
#define ASTR 136                  // LDS row stride (bf16): 272B -> 2-way alias = free

#define NTAB_CH (VOCAB1 * E_ / 8) // 800016 short8-chunks in the bf16 table

typedef __attribute__((ext_vector_type(8))) short short8;
typedef __attribute__((ext_vector_type(4))) float floatx4;

static __device__ __forceinline__ short f2bf(float f) {
    union { __hip_bfloat16 h; short s; } u;
    u.h = __float2bfloat16(f);
    return u.s;
}

__device__ __forceinline__ void atomicMaxFloat(float* addr, float v) {
    if (v >= 0.0f) atomicMax((int*)addr, __float_as_int(v));
    else           atomicMin((unsigned int*)addr, __float_as_uint(v));
}

// ---- prep (primary): bf16 table + cnn_w + att_w into ws, init out to -inf ----
__global__ void prep_full(const float* __restrict__ emb, const float* __restrict__ cnn_w,
                          const float* __restrict__ att_w,
                          short* __restrict__ tab, short* __restrict__ wsw,
                          short* __restrict__ wsatt, float* __restrict__ out) {
    int i = blockIdx.x * 256 + threadIdx.x;
    if (i < NTAB_CH) {
        const float4* s = (const float4*)emb + (size_t)i * 2;
        float4 a = s[0], b = s[1];
        short8 o = { f2bf(a.x), f2bf(a.y), f2bf(a.z), f2bf(a.w),
                     f2bf(b.x), f2bf(b.y), f2bf(b.z), f2bf(b.w) };
        *(short8*)(tab + (size_t)i * 8) = o;
        return;
    }
    i -= NTAB_CH;
    if (i < OC_ * E_ / 8) {
        const float4* s = (const float4*)cnn_w + (size_t)i * 2;
        float4 a = s[0], b = s[1];
        short8 o = { f2bf(a.x), f2bf(a.y), f2bf(a.z), f2bf(a.w),
                     f2bf(b.x), f2bf(b.y), f2bf(b.z), f2bf(b.w) };
        *(short8*)(wsw + (size_t)i * 8) = o;
        return;
    }
    i -= OC_ * E_ / 8;
    if (i < WIN_ * E_ / 8) {
        const float4* s = (const float4*)att_w + (size_t)i * 2;
        float4 a = s[0], b = s[1];
        short8 o = { f2bf(a.x), f2bf(a.y), f2bf(a.z), f2bf(a.w),
                     f2bf(b.x), f2bf(b.y), f2bf(b.z), f2bf(b.w) };
        *(short8*)(wsatt + (size_t)i * 8) = o;
        return;
    }
    i -= WIN_ * E_ / 8;
    if (i < B_ * OC_ / 4) {
        float4 v = make_float4(-INFINITY, -INFINITY, -INFINITY, -INFINITY);
        *(float4*)(out + (size_t)i * 4) = v;
    }
}

// ---- prep (fallback, small ws): cnn_w + att_w bf16, init out ----
__global__ void prep_small(const float* __restrict__ cnn_w, const float* __restrict__ att_w,
                           short* __restrict__ wsw, short* __restrict__ wsatt,
                           float* __restrict__ out) {
    int i = blockIdx.x * 256 + threadIdx.x;
    if (i < OC_ * E_)  wsw[i]   = f2bf(cnn_w[i]);
    if (i < WIN_ * E_) wsatt[i] = f2bf(att_w[i]);
    if (i < B_ * OC_)  out[i]   = -INFINITY;
}

// ---- main: NT pipelined 64-token tiles per block ----
template <bool TAB_BF16>
__launch_bounds__(256, 3)
__global__ void local_attn_main(const int* __restrict__ x,
                                const short* __restrict__ tab,   // bf16 table (primary)
                                const float* __restrict__ emb,   // fp32 table (fallback)
                                const float* __restrict__ att_b_p,
                                const short* __restrict__ wsw,   // bf16 cnn_w
                                const short* __restrict__ wsatt, // bf16 att_w
                                float* __restrict__ out) {
    __shared__ short sh_a[2][ROWS * ASTR];   // 2 x 21760 B (bf16 embed rows)
    __shared__ short sh_att[16 * ASTR];      // 4352 B (taps 0-4 real, rest zero)
    __shared__ float sh_r[ROWS * 8];         // per-row per-tap dots
    __shared__ float sh_score[TT];

    const int tid  = threadIdx.x;
    const int lane = tid & 63;
    const int w    = tid >> 6;               // wave 0..3
    const int b    = blockIdx.y;
    const int t0   = blockIdx.x * BTOK;
    const int l15  = lane & 15;
    const int quad = lane >> 4;
    const int w0   = w & 1;                  // m half
    const int w1   = w >> 1;                 // n half

    const int rbase = tid >> 4;              // gather: rows rbase+16k, chunk c
    const int c     = tid & 15;

    // ---- B fragments (cnn_w) in registers: [j][ks] ----
    short8 Bf[4][4];
    #pragma unroll
    for (int j = 0; j < 4; j++)
        #pragma unroll
        for (int ks = 0; ks < 4; ks++)
            Bf[j][ks] = *(const short8*)(wsw + (size_t)(w1 * 64 + j * 16 + l15) * E_ + ks * 32 + quad * 8);

    // ---- stage att_w -> LDS (zero-padded to 16 taps) ----
    {
        int o = tid >> 4, cc = tid & 15;
        short8 v = (short8){0,0,0,0,0,0,0,0};
        if (o < WIN_) v = *(const short8*)(wsatt + o * E_ + cc * 8);
        *(short8*)(&sh_att[o * ASTR + cc * 8]) = v;
    }

    // ---- gather tile 0 ----
    short8 g[5];
    float4 gf[5][2];
    #pragma unroll
    for (int k = 0; k < 5; k++) {
        int row = rbase + 16 * k;
        int t   = t0 + row - PAD_;
        bool ok = (row < REAL_ROWS && t >= 0 && t < T_);
        if (TAB_BF16) {
            short8 v = (short8){0,0,0,0,0,0,0,0};
            if (ok) { int idx = x[b * T_ + t]; v = *(const short8*)(tab + (size_t)idx * E_ + c * 8); }
            g[k] = v;
        } else {
            float4 z = make_float4(0.f,0.f,0.f,0.f);
            gf[k][0] = z; gf[k][1] = z;
            if (ok) {
                int idx = x[b * T_ + t];
                const float4* p = (const float4*)(emb + (size_t)idx * E_ + c * 8);
                gf[k][0] = p[0]; gf[k][1] = p[1];
            }
        }
    }
    #pragma unroll
    for (int k = 0; k < 5; k++) {
        int row = rbase + 16 * k;
        short8 v;
        if (TAB_BF16) v = g[k];
        else v = (short8){ f2bf(gf[k][0].x), f2bf(gf[k][0].y), f2bf(gf[k][0].z), f2bf(gf[k][0].w),
                           f2bf(gf[k][1].x), f2bf(gf[k][1].y), f2bf(gf[k][1].z), f2bf(gf[k][1].w) };
        *(short8*)(&sh_a[0][row * ASTR + c * 8]) = v;
    }
    __syncthreads();

    const float attb = att_b_p[0];
    float mm[4] = { -INFINITY, -INFINITY, -INFINITY, -INFINITY };

    for (int it = 0; it < NT; it++) {
        const int cur = it & 1;
        const short* A = &sh_a[cur][0];

        // 1) issue next tile's gather (loads only; LDS write deferred)
        if (it + 1 < NT) {
            int tn0 = t0 + (it + 1) * TT;
            #pragma unroll
            for (int k = 0; k < 5; k++) {
                int row = rbase + 16 * k;
                int t   = tn0 + row - PAD_;
                bool ok = (row < REAL_ROWS && t >= 0 && t < T_);
                if (TAB_BF16) {
                    short8 v = (short8){0,0,0,0,0,0,0,0};
                    if (ok) { int idx = x[b * T_ + t]; v = *(const short8*)(tab + (size_t)idx * E_ + c * 8); }
                    g[k] = v;
                } else {
                    float4 z = make_float4(0.f,0.f,0.f,0.f);
                    gf[k][0] = z; gf[k][1] = z;
                    if (ok) {
                        int idx = x[b * T_ + t];
                        const float4* p = (const float4*)(emb + (size_t)idx * E_ + c * 8);
                        gf[k][0] = p[0]; gf[k][1] = p[1];
                    }
                }
            }
        }

        // 2) scores via MFMA -> sh_r
        for (int mt = w; mt < 5; mt += 4) {
            floatx4 acc = (floatx4){0.f, 0.f, 0.f, 0.f};
            #pragma unroll
            for (int ks = 0; ks < 4; ks++) {
                short8 a  = *(const short8*)(&A[(mt * 16 + l15) * ASTR + ks * 32 + quad * 8]);
                short8 bs = *(const short8*)(&sh_att[l15 * ASTR + ks * 32 + quad * 8]);
                acc = __builtin_amdgcn_mfma_f32_16x16x32_bf16(a, bs, acc, 0, 0, 0);
            }
            if (l15 < 8) {
                #pragma unroll
                for (int r = 0; r < 4; r++)
                    sh_r[(mt * 16 + quad * 4 + r) * 8 + l15] = acc[r];
            }
        }
        __syncthreads();                       // (a) sh_r ready

        // 3) sigmoid window sum (wave 0 territory), overlapped with GEMM below
        if (tid < TT) {
            float s = attb;
            #pragma unroll
            for (int k = 0; k < WIN_; k++) s += sh_r[(tid + k) * 8 + k];
            sh_score[tid] = 1.0f / (1.0f + __expf(-s));
        }

        // 4) GEMM 64x128x128 (wave: 2 m-tiles x 4 n-tiles)
        floatx4 acc[2][4];
        #pragma unroll
        for (int i = 0; i < 2; i++)
            #pragma unroll
            for (int j = 0; j < 4; j++) acc[i][j] = (floatx4){0.f, 0.f, 0.f, 0.f};

        #pragma unroll
        for (int ks = 0; ks < 4; ks++) {
            int ko = ks * 32 + quad * 8;
            short8 a0 = *(const short8*)(&A[(PAD_ + w0 * 32 +  0 + l15) * ASTR + ko]);
            short8 a1 = *(const short8*)(&A[(PAD_ + w0 * 32 + 16 + l15) * ASTR + ko]);
            #pragma unroll
            for (int j = 0; j < 4; j++) {
                acc[0][j] = __builtin_amdgcn_mfma_f32_16x16x32_bf16(a0, Bf[j][ks], acc[0][j], 0, 0, 0);
                acc[1][j] = __builtin_amdgcn_mfma_f32_16x16x32_bf16(a1, Bf[j][ks], acc[1][j], 0, 0, 0);
            }
        }
        __syncthreads();                       // (b) sh_score ready

        // 5) epilogue: scale by score, fold into running max
        float sc[2][4];
        #pragma unroll
        for (int i = 0; i < 2; i++)
            #pragma unroll
            for (int r = 0; r < 4; r++)
                sc[i][r] = sh_score[w0 * 32 + i * 16 + quad * 4 + r];
        #pragma unroll
        for (int j = 0; j < 4; j++) {
            float mloc = -INFINITY;
            #pragma unroll
            for (int i = 0; i < 2; i++)
                #pragma unroll
                for (int r = 0; r < 4; r++)
                    mloc = fmaxf(mloc, sc[i][r] * acc[i][j][r]);
            mm[j] = fmaxf(mm[j], mloc);
        }

        // 6) commit next tile's gather to the other LDS buffer
        if (it + 1 < NT) {
            #pragma unroll
            for (int k = 0; k < 5; k++) {
                int row = rbase + 16 * k;
                short8 v;
                if (TAB_BF16) v = g[k];
                else v = (short8){ f2bf(gf[k][0].x), f2bf(gf[k][0].y), f2bf(gf[k][0].z), f2bf(gf[k][0].w),
                                   f2bf(gf[k][1].x), f2bf(gf[k][1].y), f2bf(gf[k][1].z), f2bf(gf[k][1].w) };
                *(short8*)(&sh_a[cur ^ 1][row * ASTR + c * 8]) = v;
            }
            __syncthreads();                   // (c) next buffer ready
        }
    }

    // ---- final: reduce over quads, atomicMax into out ----
    #pragma unroll
    for (int j = 0; j < 4; j++) {
        float m = mm[j];
        m = fmaxf(m, __shfl_xor(m, 16));
        m = fmaxf(m, __shfl_xor(m, 32));
        if (lane < 16)
            atomicMaxFloat(&out[b * OC_ + w1 * 64 + j * 16 + lane], m);
    }
}

__global__ void finalize_kernel(const float* __restrict__ cnn_b, float* __restrict__ out) {
    int i = blockIdx.x * 256 + threadIdx.x;
    if (i < B_ * OC_) out[i] = tanhf(out[i] + cnn_b[i & (OC_ - 1)]);
}

extern "C" void kernel_launch(void* const* d_in, const int* in_sizes, int n_in,
                              void* d_out, int out_size, void* d_ws, size_t ws_size,
                              hipStream_t stream) {
    const int*   x     = (const int*)d_in[0];
    const float* emb   = (const float*)d_in[1];
    const float* att_w = (const float*)d_in[2];
    const float* att_b = (const float*)d_in[3];
    const float* cnn_w = (const float*)d_in[4];
    const float* cnn_b = (const float*)d_in[5];
    float* out = (float*)d_out;

    const size_t tab_elems = (size_t)VOCAB1 * E_;                 // 6,400,128 bf16
    const size_t need = tab_elems * 2 + OC_ * E_ * 2 + WIN_ * E_ * 2 + 64;

    dim3 grid(T_ / BTOK, B_);   // (8, 256)

    if (ws_size >= need) {
        short* tab    = (short*)d_ws;
        short* ws_w   = tab + tab_elems;
        short* ws_att = ws_w + OC_ * E_;
        int total = NTAB_CH + OC_ * E_ / 8 + WIN_ * E_ / 8 + B_ * OC_ / 4;
        prep_full<<<(total + 255) / 256, 256, 0, stream>>>(emb, cnn_w, att_w, tab, ws_w, ws_att, out);
        local_attn_main<true><<<grid, 256, 0, stream>>>(x, tab, emb, att_b, ws_w, ws_att, out);
    } else {
        short* ws_w   = (short*)d_ws;
        short* ws_att = ws_w + OC_ * E_;
        prep_small<<<128, 256, 0, stream>>>(cnn_w, att_w, ws_w, ws_att, out);
        local_attn_main<false><<<grid, 256, 0, stream>>>(x, (const short*)nullptr, emb, att_b, ws_w, ws_att, out);
    }
    finalize_kernel<<<(B_ * OC_ + 255) / 256, 256, 0, stream>>>(cnn_b, out);
}

// Round 4
// 123.801 us; speedup vs baseline: 4.0942x; 1.1573x over previous
//
#include <hip/hip_runtime.h>
#include <hip/hip_bf16.h>
#include <math.h>

// B,T,E,WIN,OC,VOCAB = 256,2048,128,5,128,50000
#define B_   256
#define T_   2048
#define E_   128
#define WIN_ 5
#define PAD_ 2
#define OC_  128
#define VOCAB1 50001
#define NT   8                    // 64-token tiles per block
#define TT   64
#define BTOK (NT * TT)            // 512 tokens per block
#define REAL_ROWS (TT + WIN_ - 1) // 68 rows incl. halo
#define ROWS 80                   // padded to 5 m-tiles of 16
#define ASTR 136                  // LDS row stride (bf16): 272B -> 2-way alias = free

#define NTAB_CH (VOCAB1 * E_ / 8) // 800016 short8 chunks

typedef __attribute__((ext_vector_type(8))) short short8;
typedef __attribute__((ext_vector_type(4))) float floatx4;

static __device__ __forceinline__ short f2bf(float f) {
    union { __hip_bfloat16 h; short s; } u;
    u.h = __float2bfloat16(f);
    return u.s;
}

__device__ __forceinline__ void atomicMaxFloat(float* addr, float v) {
    // works with 0xFFFFFFFF init pattern on both paths
    if (v >= 0.0f) atomicMax((int*)addr, __float_as_int(v));
    else           atomicMin((unsigned int*)addr, __float_as_uint(v));
}

// ---- prep (primary): bf16 table + cnn_w + att_w into ws ----
__global__ void prep_full(const float* __restrict__ emb, const float* __restrict__ cnn_w,
                          const float* __restrict__ att_w,
                          short* __restrict__ tab, short* __restrict__ wsw,
                          short* __restrict__ wsatt) {
    int i = blockIdx.x * 256 + threadIdx.x;
    const float* src;
    short* dst;
    if (i < NTAB_CH) { src = emb; dst = tab; }
    else if ((i -= NTAB_CH) < OC_ * E_ / 8) { src = cnn_w; dst = wsw; }
    else if ((i -= OC_ * E_ / 8) < WIN_ * E_ / 8) { src = att_w; dst = wsatt; }
    else return;
    const float4* s = (const float4*)src + (size_t)i * 2;
    float4 a = s[0], b = s[1];
    short8 o = { f2bf(a.x), f2bf(a.y), f2bf(a.z), f2bf(a.w),
                 f2bf(b.x), f2bf(b.y), f2bf(b.z), f2bf(b.w) };
    *(short8*)(dst + (size_t)i * 8) = o;
}

// ---- prep (fallback): weights only ----
__global__ void prep_small(const float* __restrict__ cnn_w, const float* __restrict__ att_w,
                           short* __restrict__ wsw, short* __restrict__ wsatt) {
    int i = blockIdx.x * 256 + threadIdx.x;
    if (i < OC_ * E_)  wsw[i]   = f2bf(cnn_w[i]);
    if (i < WIN_ * E_) wsatt[i] = f2bf(att_w[i]);
}

template <bool TAB_BF16>
__launch_bounds__(256, 4)
__global__ void local_attn_main(const int* __restrict__ x,
                                const short* __restrict__ tab,
                                const float* __restrict__ emb,
                                const float* __restrict__ att_b_p,
                                const short* __restrict__ wsw,
                                const short* __restrict__ wsatt,
                                const float* __restrict__ cnn_b,
                                float* __restrict__ out) {
    __shared__ short sh_a[ROWS * ASTR];     // 21760 B (one tile of bf16 embed rows)
    __shared__ short sh_att[16 * ASTR];     // 4352 B  (taps 0-4 real, rest zero)
    __shared__ float sh_r[ROWS * 8];        // 2560 B
    __shared__ float sh_score[TT];          // 256 B
    __shared__ int   sh_idx[NT * ROWS];     // 2560 B   -> 31.5 KB total

    const int tid  = threadIdx.x;
    const int lane = tid & 63;
    const int w    = tid >> 6;              // wave 0..3 -> o-range [w*32, w*32+32)
    const int b    = blockIdx.y;
    const int t0   = blockIdx.x * BTOK;
    const int l15  = lane & 15;
    const int quad = lane >> 4;
    const int rbase = tid >> 4;             // gather rows rbase+16k, chunk c
    const int c     = tid & 15;

    // ---- stage all tile indices once ----
    for (int i = tid; i < NT * ROWS; i += 256) {
        int tile = i / ROWS, row = i - tile * ROWS;
        int t = t0 + tile * TT + row - PAD_;
        sh_idx[i] = (row < REAL_ROWS && t >= 0 && t < T_) ? x[b * T_ + t] : -1;
    }
    // ---- stage att_w (zero-padded to 16 taps) ----
    {
        int o = tid >> 4, cc = tid & 15;
        short8 v = (short8){0,0,0,0,0,0,0,0};
        if (o < WIN_) v = *(const short8*)(wsatt + o * E_ + cc * 8);
        *(short8*)(&sh_att[o * ASTR + cc * 8]) = v;
    }
    // ---- B fragments: wave covers 32 cols: Bf[j][ks], j<2 ----
    short8 Bf[2][4];
    #pragma unroll
    for (int j = 0; j < 2; j++)
        #pragma unroll
        for (int ks = 0; ks < 4; ks++)
            Bf[j][ks] = *(const short8*)(wsw + (size_t)(w * 32 + j * 16 + l15) * E_ + ks * 32 + quad * 8);
    __syncthreads();

    // ---- gather + commit tile 0 ----
    short8 g[5];
    #pragma unroll
    for (int k = 0; k < 5; k++) {
        int row = rbase + 16 * k;
        int idx = sh_idx[row];
        short8 v = (short8){0,0,0,0,0,0,0,0};
        if (idx >= 0) {
            if (TAB_BF16) v = *(const short8*)(tab + (size_t)idx * E_ + c * 8);
            else {
                const float4* p = (const float4*)(emb + (size_t)idx * E_ + c * 8);
                float4 p0 = p[0], p1 = p[1];
                v = (short8){ f2bf(p0.x), f2bf(p0.y), f2bf(p0.z), f2bf(p0.w),
                              f2bf(p1.x), f2bf(p1.y), f2bf(p1.z), f2bf(p1.w) };
            }
        }
        g[k] = v;
    }
    #pragma unroll
    for (int k = 0; k < 5; k++)
        *(short8*)(&sh_a[(rbase + 16 * k) * ASTR + c * 8]) = g[k];
    __syncthreads();

    const float attb = att_b_p[0];
    float mm[2] = { -INFINITY, -INFINITY };

    for (int it = 0; it < NT; it++) {
        // 1) issue next tile's gathers (registers only)
        if (it + 1 < NT) {
            const int* idxp = &sh_idx[(it + 1) * ROWS];
            #pragma unroll
            for (int k = 0; k < 5; k++) {
                int idx = idxp[rbase + 16 * k];
                short8 v = (short8){0,0,0,0,0,0,0,0};
                if (idx >= 0) {
                    if (TAB_BF16) v = *(const short8*)(tab + (size_t)idx * E_ + c * 8);
                    else {
                        const float4* p = (const float4*)(emb + (size_t)idx * E_ + c * 8);
                        float4 p0 = p[0], p1 = p[1];
                        v = (short8){ f2bf(p0.x), f2bf(p0.y), f2bf(p0.z), f2bf(p0.w),
                                      f2bf(p1.x), f2bf(p1.y), f2bf(p1.z), f2bf(p1.w) };
                    }
                }
                g[k] = v;
            }
        }

        // 2) scores via MFMA -> sh_r
        for (int mt = w; mt < 5; mt += 4) {
            floatx4 acc = (floatx4){0.f, 0.f, 0.f, 0.f};
            #pragma unroll
            for (int ks = 0; ks < 4; ks++) {
                short8 a  = *(const short8*)(&sh_a[(mt * 16 + l15) * ASTR + ks * 32 + quad * 8]);
                short8 bs = *(const short8*)(&sh_att[l15 * ASTR + ks * 32 + quad * 8]);
                acc = __builtin_amdgcn_mfma_f32_16x16x32_bf16(a, bs, acc, 0, 0, 0);
            }
            if (l15 < 8) {
                #pragma unroll
                for (int r = 0; r < 4; r++)
                    sh_r[(mt * 16 + quad * 4 + r) * 8 + l15] = acc[r];
            }
        }
        __syncthreads();                       // (a) sh_r ready

        // 3) window sum + sigmoid
        if (tid < TT) {
            float s = attb;
            #pragma unroll
            for (int k = 0; k < WIN_; k++) s += sh_r[(tid + k) * 8 + k];
            sh_score[tid] = 1.0f / (1.0f + __expf(-s));
        }

        // 4) GEMM: full 64 rows x 32 cols per wave
        floatx4 acc[4][2];
        #pragma unroll
        for (int i = 0; i < 4; i++)
            #pragma unroll
            for (int j = 0; j < 2; j++) acc[i][j] = (floatx4){0.f, 0.f, 0.f, 0.f};

        #pragma unroll
        for (int ks = 0; ks < 4; ks++) {
            int ko = ks * 32 + quad * 8;
            #pragma unroll
            for (int i = 0; i < 4; i++) {
                short8 ai = *(const short8*)(&sh_a[(PAD_ + i * 16 + l15) * ASTR + ko]);
                acc[i][0] = __builtin_amdgcn_mfma_f32_16x16x32_bf16(ai, Bf[0][ks], acc[i][0], 0, 0, 0);
                acc[i][1] = __builtin_amdgcn_mfma_f32_16x16x32_bf16(ai, Bf[1][ks], acc[i][1], 0, 0, 0);
            }
        }
        __syncthreads();                       // (b) sh_score ready; sh_a reads done

        // 5) epilogue: scale by score, fold into running max
        #pragma unroll
        for (int i = 0; i < 4; i++) {
            #pragma unroll
            for (int r = 0; r < 4; r++) {
                float sc = sh_score[i * 16 + quad * 4 + r];
                mm[0] = fmaxf(mm[0], sc * acc[i][0][r]);
                mm[1] = fmaxf(mm[1], sc * acc[i][1][r]);
            }
        }

        // 6) commit next tile
        if (it + 1 < NT) {
            #pragma unroll
            for (int k = 0; k < 5; k++)
                *(short8*)(&sh_a[(rbase + 16 * k) * ASTR + c * 8]) = g[k];
            __syncthreads();                   // (c) sh_a ready for next iter
        }
    }

    // ---- final: quad-reduce, tanh(+bias), atomicMax ----
    #pragma unroll
    for (int j = 0; j < 2; j++) {
        float m = mm[j];
        m = fmaxf(m, __shfl_xor(m, 16));
        m = fmaxf(m, __shfl_xor(m, 32));
        if (lane < 16) {
            int o = w * 32 + j * 16 + lane;
            atomicMaxFloat(&out[b * OC_ + o], tanhf(m + cnn_b[o]));
        }
    }
}

extern "C" void kernel_launch(void* const* d_in, const int* in_sizes, int n_in,
                              void* d_out, int out_size, void* d_ws, size_t ws_size,
                              hipStream_t stream) {
    const int*   x     = (const int*)d_in[0];
    const float* emb   = (const float*)d_in[1];
    const float* att_w = (const float*)d_in[2];
    const float* att_b = (const float*)d_in[3];
    const float* cnn_w = (const float*)d_in[4];
    const float* cnn_b = (const float*)d_in[5];
    float* out = (float*)d_out;

    // out init: 0xFFFFFFFF is the identity element for the int/uint atomic-max trick
    hipMemsetAsync(d_out, 0xFF, (size_t)B_ * OC_ * sizeof(float), stream);

    const size_t tab_elems = (size_t)VOCAB1 * E_;
    const size_t need = tab_elems * 2 + OC_ * E_ * 2 + WIN_ * E_ * 2 + 64;

    dim3 grid(T_ / BTOK, B_);   // (4, 256) = 1024 blocks

    if (ws_size >= need) {
        short* tab    = (short*)d_ws;
        short* ws_w   = tab + tab_elems;
        short* ws_att = ws_w + OC_ * E_;
        int total = NTAB_CH + OC_ * E_ / 8 + WIN_ * E_ / 8;
        prep_full<<<(total + 255) / 256, 256, 0, stream>>>(emb, cnn_w, att_w, tab, ws_w, ws_att);
        local_attn_main<true><<<grid, 256, 0, stream>>>(x, tab, emb, att_b, ws_w, ws_att, cnn_b, out);
    } else {
        short* ws_w   = (short*)d_ws;
        short* ws_att = ws_w + OC_ * E_;
        prep_small<<<16, 256, 0, stream>>>(cnn_w, att_w, ws_w, ws_att);
        local_attn_main<false><<<grid, 256, 0, stream>>>(x, (const short*)nullptr, emb, att_b, ws_w, ws_att, cnn_b, out);
    }
}